// Round 12
// baseline (156.784 us; speedup 1.0000x reference)
//
#include <hip/hip_runtime.h>

#define SQRT2f 1.41421356237309515f
#define SQRT3f 1.73205080756887729f

__device__ __forceinline__ float2 cmul(float2 a, float2 b) {
  return make_float2(a.x*b.x - a.y*b.y, a.x*b.y + a.y*b.x);
}
__device__ __forceinline__ float2 cadd(float2 a, float2 b) {
  return make_float2(a.x + b.x, a.y + b.y);
}

// ---- BS 9x9 on a register 9-vector q[3*na + nb] (rows 0,8 identity) ----
__device__ __forceinline__ void bs_q(float2* q, float2 cs) {
  const float c = cs.x, s = cs.y;
  const float c2 = c*c - s*s, s2 = 2.f*c*s;
  const float cc = c*c, ss = s*s, rcs = SQRT2f*c*s;
  float2 a1=q[1], a3=q[3], a2=q[2], a4=q[4], a6=q[6], a5=q[5], a7=q[7];
  q[1] = make_float2(c*a1.x - s*a3.x, c*a1.y - s*a3.y);
  q[3] = make_float2(s*a1.x + c*a3.x, s*a1.y + c*a3.y);
  q[2] = make_float2(cc*a2.x - rcs*a4.x + ss*a6.x, cc*a2.y - rcs*a4.y + ss*a6.y);
  q[4] = make_float2(rcs*a2.x + c2*a4.x - rcs*a6.x, rcs*a2.y + c2*a4.y - rcs*a6.y);
  q[6] = make_float2(ss*a2.x + rcs*a4.x + cc*a6.x, ss*a2.y + rcs*a4.y + cc*a6.y);
  q[5] = make_float2(c2*a5.x - s2*a7.x, c2*a5.y - s2*a7.y);
  q[7] = make_float2(s2*a5.x + c2*a7.x, s2*a5.y + c2*a7.y);
}

// ---- plain BS nonet (pair 0,1; SP=81), in place ----
template<int SP>
__device__ __forceinline__ void bs_nonet(float2* __restrict__ psi, int base,
                                         float2 cs) {
  const float c = cs.x, s = cs.y;
  const float c2 = c*c - s*s, s2 = 2.f*c*s;
  const float cc = c*c, ss = s*s, rcs = SQRT2f*c*s;
  float2 a1 = psi[base+SP],   a3 = psi[base+3*SP];
  float2 a2 = psi[base+2*SP], a4 = psi[base+4*SP], a6 = psi[base+6*SP];
  float2 a5 = psi[base+5*SP], a7 = psi[base+7*SP];
  psi[base+SP]   = make_float2(c*a1.x - s*a3.x, c*a1.y - s*a3.y);
  psi[base+3*SP] = make_float2(s*a1.x + c*a3.x, s*a1.y + c*a3.y);
  psi[base+2*SP] = make_float2(cc*a2.x - rcs*a4.x + ss*a6.x,
                               cc*a2.y - rcs*a4.y + ss*a6.y);
  psi[base+4*SP] = make_float2(rcs*a2.x + c2*a4.x - rcs*a6.x,
                               rcs*a2.y + c2*a4.y - rcs*a6.y);
  psi[base+6*SP] = make_float2(ss*a2.x + rcs*a4.x + cc*a6.x,
                               ss*a2.y + rcs*a4.y + cc*a6.y);
  psi[base+5*SP] = make_float2(c2*a5.x - s2*a7.x, c2*a5.y - s2*a7.y);
  psi[base+7*SP] = make_float2(s2*a5.x + c2*a7.x, s2*a5.y + c2*a7.y);
}

// ---- fused (SQ_A ⊗ SQ_B) then BS, pair (0,1). G = A(5),B(5) ----
template<int SP>
__device__ __forceinline__ void sqbs_nonet(float2* __restrict__ psi, int base,
                                           const float2* __restrict__ G,
                                           float2 cs) {
  float2 A00=G[0],A02=G[1],A11=G[2],A20=G[3],A22=G[4];
  float2 B00=G[5],B02=G[6],B11=G[7],B20=G[8],B22=G[9];
  float2 v[3][3];
#pragma unroll
  for (int j = 0; j < 3; ++j)
#pragma unroll
    for (int jb = 0; jb < 3; ++jb) v[j][jb] = psi[base + j*3*SP + jb*SP];
  float2 q[9];
  {
    float2 t[3][3];
#pragma unroll
    for (int j = 0; j < 3; ++j) {
      t[j][0] = cadd(cmul(B00,v[j][0]), cmul(B02,v[j][2]));
      t[j][1] = cmul(B11,v[j][1]);
      t[j][2] = cadd(cmul(B20,v[j][0]), cmul(B22,v[j][2]));
    }
#pragma unroll
    for (int ib = 0; ib < 3; ++ib) {
      q[ib]   = cadd(cmul(A00,t[0][ib]), cmul(A02,t[2][ib]));
      q[3+ib] = cmul(A11,t[1][ib]);
      q[6+ib] = cadd(cmul(A20,t[0][ib]), cmul(A22,t[2][ib]));
    }
  }
  bs_q(q, cs);
#pragma unroll
  for (int i = 0; i < 9; ++i) psi[base + (i/3)*3*SP + (i%3)*SP] = q[i];
}

// ---- fused (DPK_A ⊗ DPK_B dense) then BS, pair (0,1). G = A(9),B(9) ----
template<int SP>
__device__ __forceinline__ void dpbs_nonet(float2* __restrict__ psi, int base,
                                           const float2* __restrict__ G,
                                           float2 cs) {
  const float2* A = G; const float2* B = G + 9;
  float2 v[3][3];
#pragma unroll
  for (int j = 0; j < 3; ++j)
#pragma unroll
    for (int jb = 0; jb < 3; ++jb) v[j][jb] = psi[base + j*3*SP + jb*SP];
  float2 q[9];
  {
    float2 t[3][3];
#pragma unroll
    for (int j = 0; j < 3; ++j)
#pragma unroll
      for (int ib = 0; ib < 3; ++ib)
        t[j][ib] = cadd(cadd(cmul(B[ib*3+0],v[j][0]), cmul(B[ib*3+1],v[j][1])),
                        cmul(B[ib*3+2],v[j][2]));
#pragma unroll
    for (int i = 0; i < 3; ++i)
#pragma unroll
      for (int ib = 0; ib < 3; ++ib)
        q[i*3+ib] = cadd(cadd(cmul(A[i*3+0],t[0][ib]), cmul(A[i*3+1],t[1][ib])),
                         cmul(A[i*3+2],t[2][ib]));
  }
  bs_q(q, cs);
#pragma unroll
  for (int i = 0; i < 9; ++i) psi[base + (i/3)*3*SP + (i%3)*SP] = q[i];
}

// ---- 81-thread cube sweep: thread (cube, h) holds v[mid][lo] slice hi=h.
// fold(A on mid, B on lo) + BS(mid,lo) local; then re-partition to lo=h plane
// via rotate-offset shuffles (source expression evaluates to dest's element);
// BS(hi,mid) local; write back plane lo=h. lb3 = first lane of triple.
template<int FOLD, int SH, int SM, int SL>
__device__ __forceinline__ void cube81(float2* __restrict__ psi, int base,
                                       int h, int lb3,
                                       const float2* __restrict__ G,
                                       float2 csM, float2 csH) {
  float2 v[9];
#pragma unroll
  for (int m = 0; m < 3; ++m)
#pragma unroll
    for (int l = 0; l < 3; ++l) v[m*3+l] = psi[base + h*SH + m*SM + l*SL];
  if (FOLD == 1) {       // sparse SQ: A(5) on mid, B(5) on lo
    float2 A00=G[0],A02=G[1],A11=G[2],A20=G[3],A22=G[4];
    float2 B00=G[5],B02=G[6],B11=G[7],B20=G[8],B22=G[9];
#pragma unroll
    for (int m = 0; m < 3; ++m) {         // B along lo
      float2 u0=v[m*3], u2=v[m*3+2];
      v[m*3]   = cadd(cmul(B00,u0), cmul(B02,u2));
      v[m*3+1] = cmul(B11, v[m*3+1]);
      v[m*3+2] = cadd(cmul(B20,u0), cmul(B22,u2));
    }
#pragma unroll
    for (int l = 0; l < 3; ++l) {         // A along mid
      float2 u0=v[l], u2=v[6+l];
      v[l]   = cadd(cmul(A00,u0), cmul(A02,u2));
      v[3+l] = cmul(A11, v[3+l]);
      v[6+l] = cadd(cmul(A20,u0), cmul(A22,u2));
    }
  }
  if (FOLD == 2) {       // dense DPK: A(9) on mid, B(9) on lo
#pragma unroll
    for (int m = 0; m < 3; ++m) {         // B along lo
      float2 u0=v[m*3], u1=v[m*3+1], u2=v[m*3+2];
      v[m*3]   = cadd(cadd(cmul(G[9+0],u0),cmul(G[9+1],u1)),cmul(G[9+2],u2));
      v[m*3+1] = cadd(cadd(cmul(G[9+3],u0),cmul(G[9+4],u1)),cmul(G[9+5],u2));
      v[m*3+2] = cadd(cadd(cmul(G[9+6],u0),cmul(G[9+7],u1)),cmul(G[9+8],u2));
    }
#pragma unroll
    for (int l = 0; l < 3; ++l) {         // A along mid
      float2 u0=v[l], u1=v[3+l], u2=v[6+l];
      v[l]   = cadd(cadd(cmul(G[0],u0),cmul(G[1],u1)),cmul(G[2],u2));
      v[3+l] = cadd(cadd(cmul(G[3],u0),cmul(G[4],u1)),cmul(G[5],u2));
      v[6+l] = cadd(cadd(cmul(G[6],u0),cmul(G[7],u1)),cmul(G[8],u2));
    }
  }
  bs_q(v, csM);                           // BS(mid,lo) local, q = 3*mid+lo
  // Re-partition: thread h needs a[3*hi+m] = amp(hi, m, lo=h).
  // d=0 (hi=h): own v[3m+h].
  // d=1 (hi=(h+1)%3): shfl of expr v[3m+(h+2)%3] from lane lb3+(h+1)%3
  //   -> source (h'=(h+1)%3) provides v[3m+(h'+2)%3] = v[3m+h]. ✓
  // d=2 (hi=(h+2)%3): shfl of expr v[3m+(h+1)%3] from lane lb3+(h+2)%3. ✓
  const int hp1 = (h==2) ? 0 : h+1;
  const int hp2 = (h==0) ? 2 : h-1;
  const int l1 = lb3 + hp1, l2 = lb3 + hp2;
  float2 a[9];
#pragma unroll
  for (int m = 0; m < 3; ++m) {
    float2 own = (h==0) ? v[3*m]   : (h==1) ? v[3*m+1] : v[3*m+2];
    float2 e1  = (h==0) ? v[3*m+2] : (h==1) ? v[3*m]   : v[3*m+1]; // (h+2)%3
    float2 e2  = (h==0) ? v[3*m+1] : (h==1) ? v[3*m+2] : v[3*m];   // (h+1)%3
    float2 r1, r2;
    r1.x = __shfl(e1.x, l1, 64); r1.y = __shfl(e1.y, l1, 64);
    r2.x = __shfl(e2.x, l2, 64); r2.y = __shfl(e2.y, l2, 64);
    // a[3*hi+m]: hi==h -> own; hi==(h+1)%3 -> r1; hi==(h+2)%3 -> r2
    a[0+m] = (h==0) ? own : (h==2) ? r1 : r2;
    a[3+m] = (h==1) ? own : (h==0) ? r1 : r2;
    a[6+m] = (h==2) ? own : (h==1) ? r1 : r2;
  }
  bs_q(a, csH);                           // BS(hi,mid), q = 3*hi+mid
#pragma unroll
  for (int hi = 0; hi < 3; ++hi)
#pragma unroll
    for (int m = 0; m < 3; ++m)
      psi[base + hi*SH + m*SM + h*SL] = a[3*hi+m];
}

#define BASE5(g, s0,s1,s2,s3,s4) ({ int _d=(g); int _b=(_d%3)*(s0); _d/=3; \
  _b += (_d%3)*(s1); _d/=3; _b += (_d%3)*(s2); _d/=3; _b += (_d%3)*(s3); _d/=3; \
  _b += (_d%3)*(s4); _b; })

// DPK(L,mode)[i][j] = Kerr_i * U_disp[i][j] * phase^j (th2-layer phases)
__device__ __forceinline__ float2 dpk_entry(const float* __restrict__ dr,
                                            const float* __restrict__ th2,
                                            const float* __restrict__ kp,
                                            int L, int mode, int i, int j) {
  float sn, cn; sincosf(SQRT3f*dr[L*6+mode], &sn, &cn);
  float sw = sn*(1.f/SQRT3f), cw = (1.f-cn)*(1.f/3.f);
  float U;
  if      (i==0) U = (j==0) ? (1.f-cw)     : (j==1) ? (-sw)         : (SQRT2f*cw);
  else if (i==1) U = (j==0) ? (sw)         : (j==1) ? (1.f-3.f*cw)  : (-SQRT2f*sw);
  else           U = (j==0) ? (SQRT2f*cw)  : (j==1) ? (SQRT2f*sw)   : (1.f-2.f*cw);
  float2 ph = make_float2(1.f, 0.f);
  if (mode < 5) { float ps, pc; sincosf(th2[L*35+29+mode], &ps, &pc);
                  ph = make_float2(pc, ps); }
  float2 phj = (j==0) ? make_float2(1.f,0.f) : (j==1) ? ph : cmul(ph, ph);
  float ks, kc; sincosf(0.001f*kp[L*6+mode], &ks, &kc);
  float2 k1 = make_float2(kc, ks);
  float2 ki = (i==0) ? make_float2(1.f,0.f)
            : (i==1) ? k1 : cmul(cmul(k1,k1), cmul(k1,k1));
  float2 t = cmul(phj, ki);
  return make_float2(U*t.x, U*t.y);
}

// gtab (float2):
// [0,180)   BS (c,s): idx = (L*2+pass)*15 + pos (application order)
// [180,360) SQG: 180 + L*30 + c*10 : A(5) mode 2c, B(5) mode 2c+1 (th1 phases)
// [360,630) DPG: 360 + Ls*54 + c*18 : A(9) mode 2c, B(9) mode 2c+1 (layers 0..4)
// [630,684) Meas M_m = DPK(5,m)† X3 DPK(5,m): 630 + m*9 + i*3+j
// [684,690) init disp (sw,cw) per mode
__global__ __launch_bounds__(128)
void cvnn_kernel(const float* __restrict__ x,
                 const float* __restrict__ th1,
                 const float* __restrict__ th2,
                 const float* __restrict__ sr,
                 const float* __restrict__ dr,
                 const float* __restrict__ kp,
                 float* __restrict__ out) {
  __shared__ float2 psi[729];
  __shared__ float2 gtab[690];
  __shared__ float red[12];

  const int tid = threadIdx.x;
  const int bidx = blockIdx.x;

  // ---- build gate table ----
  for (int f = tid; f < 690; f += 128) {
    float sn, cn; float2 v;
    if (f < 180) {
      int Lp = f/15, pos = f%15;
      int L = Lp/2, pass = Lp%2;
      float th = (pass ? th2 : th1)[L*35 + pos];
      sincosf(th, &sn, &cn); v = make_float2(cn, sn);
    } else if (f < 360) {
      int i = f - 180; int Lc = i/10, e = i%10;
      int L = Lc/3, c3 = Lc%3;
      int mode = 2*c3 + (e >= 5); int ee = e%5;
      float Sq, Cq; sincosf(0.25f*SQRT2f*sr[L*6+mode], &Sq, &Cq);
      float2 ph = make_float2(1.f, 0.f);
      if (mode < 5) { float ps, pc; sincosf(th1[L*35+29+mode], &ps, &pc);
                      ph = make_float2(pc, ps); }
      float2 ph2 = cmul(ph, ph);
      if      (ee == 0) v = make_float2(Cq, 0.f);
      else if (ee == 1) v = make_float2(Sq*ph2.x, Sq*ph2.y);
      else if (ee == 2) v = ph;
      else if (ee == 3) v = make_float2(-Sq, 0.f);
      else              v = make_float2(Cq*ph2.x, Cq*ph2.y);
    } else if (f < 630) {
      int i = f - 360; int Ld = i/18, e = i%18;
      int Ls = Ld/3, c3 = Ld%3;
      int mode = 2*c3 + (e >= 9); int ee = e%9;
      v = dpk_entry(dr, th2, kp, Ls, mode, ee/3, ee%3);
    } else if (f < 684) {
      int i = f - 630; int m = i/9, e = i%9;
      int ii = e/3, jj = e%3;
      float2 D0i = dpk_entry(dr, th2, kp, 5, m, 0, ii);
      float2 D1i = dpk_entry(dr, th2, kp, 5, m, 1, ii);
      float2 D2i = dpk_entry(dr, th2, kp, 5, m, 2, ii);
      float2 D0j = dpk_entry(dr, th2, kp, 5, m, 0, jj);
      float2 D1j = dpk_entry(dr, th2, kp, 5, m, 1, jj);
      float2 D2j = dpk_entry(dr, th2, kp, 5, m, 2, jj);
      float2 c0 = make_float2(D0i.x, -D0i.y);
      float2 c1 = make_float2(D1i.x, -D1i.y);
      float2 c2 = make_float2(D2i.x, -D2i.y);
      float2 acc = cmul(c0, D1j);
      float2 tmp = make_float2(D0j.x + SQRT2f*D2j.x, D0j.y + SQRT2f*D2j.y);
      acc = cadd(acc, cmul(c1, tmp));
      acc = cadd(acc, cmul(c2, make_float2(SQRT2f*D1j.x, SQRT2f*D1j.y)));
      v = acc;
    } else {
      int mode = f - 684;
      sincosf(SQRT3f*x[bidx*6 + mode], &sn, &cn);
      v = make_float2(sn*(1.f/SQRT3f), (1.f-cn)*(1.f/3.f));
    }
    gtab[f] = v;
  }
  __syncthreads();

  // ---- init: product state of displaced |0> ----
  for (int idx = tid; idx < 729; idx += 128) {
    float pr = 1.f; int d = idx;
#pragma unroll
    for (int mm = 5; mm >= 0; --mm) {
      int n = d % 3; d /= 3;
      float2 dc = gtab[684 + mm];
      pr *= (n==0) ? (1.f-dc.y) : (n==1) ? dc.x : SQRT2f*dc.y;
    }
    psi[idx] = make_float2(pr, 0.f);
  }

  // ---- per-thread bases ----
  const int g = (tid < 81) ? tid : 0;      // pair(0,1) nonet id (tid<81 active)
  const int b0 = g;                        // SP=81
  // cube threads: triples at consecutive lanes; never straddle a wave
  const int lane = tid & 63, wv = tid >> 6;
  const bool cact = (wv == 0) ? (lane < 63) : (lane < 18);
  const int lc = lane / 3;
  const int cc = (wv == 0) ? lc : (21 + lc);   // cube id 0..26
  const int ch = lane % 3;
  const int lb3 = lc * 3;
  const int q0 = cc/9, q1 = (cc%9)/3, q2 = cc%3;
  const int cbase123 = q0*243 + q1*3 + q2;     // fixed (n0,n4,n5)
  const int cbase345 = q0*243 + q1*81 + q2*27; // fixed (n0,n1,n2)
  __syncthreads();

#define W81_BS(GI)      { if (tid < 81) bs_nonet<81>(psi, b0, gtab[GI]); \
    __syncthreads(); }
#define W81_SQBS(GS,GI) { if (tid < 81) sqbs_nonet<81>(psi, b0, &gtab[GS], gtab[GI]); \
    __syncthreads(); }
#define W81_DPBS(GD,GI) { if (tid < 81) dpbs_nonet<81>(psi, b0, &gtab[GD], gtab[GI]); \
    __syncthreads(); }
#define C123(F,GP,GIM,GIH) { if (cact) \
    cube81<F,81,27,9>(psi, cbase123, ch, lb3, GP, gtab[GIM], gtab[GIH]); \
    __syncthreads(); }
#define C345(F,GP,GIM,GIH) { if (cact) \
    cube81<F,9,3,1>(psi, cbase345, ch, lb3, GP, gtab[GIM], gtab[GIH]); \
    __syncthreads(); }

#pragma unroll
  for (int L = 0; L < 6; ++L) {
    {  // th1 pass: folds previous layer's DPK (L>=1)
      const int PB = (L*2)*15;
      if (L == 0) {
        W81_BS(PB+0);
        C123(0, (const float2*)nullptr, PB+1, PB+3);
        C345(0, (const float2*)nullptr, PB+2, PB+4);
      } else {
        const int gd = 360 + (L-1)*54;
        W81_DPBS(gd+0, PB+0);
        C123(2, &gtab[gd+18], PB+1, PB+3);
        C345(2, &gtab[gd+36], PB+2, PB+4);
      }
      W81_BS(PB+5);
      C123(0, (const float2*)nullptr, PB+6, PB+8);
      C345(0, (const float2*)nullptr, PB+7, PB+9);
      W81_BS(PB+10);
      C123(0, (const float2*)nullptr, PB+11, PB+13);
      C345(0, (const float2*)nullptr, PB+12, PB+14);
    }
    {  // th2 pass: folds this layer's SQ (+th1 phases)
      const int PB = (L*2+1)*15, gs = 180 + L*30;
      W81_SQBS(gs+0, PB+0);
      C123(1, &gtab[gs+10], PB+1, PB+3);
      C345(1, &gtab[gs+20], PB+2, PB+4);
      W81_BS(PB+5);
      C123(0, (const float2*)nullptr, PB+6, PB+8);
      C345(0, (const float2*)nullptr, PB+7, PB+9);
      W81_BS(PB+10);
      C123(0, (const float2*)nullptr, PB+11, PB+13);
      C345(0, (const float2*)nullptr, PB+12, PB+14);
    }
  }

  // ---- <X_m> via folded Hermitian M_m = DPK(5,m)† X DPK(5,m) ----
  float xs[6] = {0.f,0.f,0.f,0.f,0.f,0.f};
  for (int it = 0; it < 2; ++it) {
    int t = tid + (it << 7);
    if (t < 243) {
#define XACC(m, SS, BB) { int b_ = (BB); \
      const float2* M_ = &gtab[630 + (m)*9]; \
      float d0 = M_[0].x, d1 = M_[4].x, d2 = M_[8].x; \
      float2 M01 = M_[1], M02 = M_[2], M12 = M_[5]; \
      float2 a_ = psi[b_]; float2 e_ = psi[b_+(SS)]; float2 f_ = psi[b_+2*(SS)]; \
      xs[m] += d0*(a_.x*a_.x + a_.y*a_.y) + d1*(e_.x*e_.x + e_.y*e_.y) \
             + d2*(f_.x*f_.x + f_.y*f_.y) \
        + 2.f*(M01.x*(a_.x*e_.x + a_.y*e_.y) - M01.y*(a_.x*e_.y - a_.y*e_.x)) \
        + 2.f*(M02.x*(a_.x*f_.x + a_.y*f_.y) - M02.y*(a_.x*f_.y - a_.y*f_.x)) \
        + 2.f*(M12.x*(e_.x*f_.x + e_.y*f_.y) - M12.y*(e_.x*f_.y - e_.y*f_.x)); }
      XACC(0, 243, BASE5(t, 1, 3, 9, 27, 81));
      XACC(1, 81,  BASE5(t, 1, 3, 9, 27, 243));
      XACC(2, 27,  BASE5(t, 1, 3, 9, 81, 243));
      XACC(3, 9,   BASE5(t, 1, 3, 27, 81, 243));
      XACC(4, 3,   BASE5(t, 1, 9, 27, 81, 243));
      XACC(5, 1,   BASE5(t, 3, 9, 27, 81, 243));
    }
  }
  const int wid = tid >> 6;
#pragma unroll
  for (int m = 0; m < 6; ++m) {
    float v = xs[m];
    for (int off = 32; off > 0; off >>= 1) v += __shfl_down(v, off);
    if ((tid & 63) == 0) red[wid*6 + m] = v;
  }
  __syncthreads();
  if (tid < 6) out[bidx*6 + tid] = red[tid] + red[6 + tid];
}

extern "C" void kernel_launch(void* const* d_in, const int* in_sizes, int n_in,
                              void* d_out, int out_size, void* d_ws, size_t ws_size,
                              hipStream_t stream) {
  const float* x  = (const float*)d_in[0];
  const float* t1 = (const float*)d_in[1];
  const float* t2 = (const float*)d_in[2];
  const float* sr = (const float*)d_in[3];
  const float* dr = (const float*)d_in[4];
  const float* kp = (const float*)d_in[5];
  const int B = in_sizes[0] / 6;
  cvnn_kernel<<<B, 128, 0, stream>>>(x, t1, t2, sr, dr, kp, (float*)d_out);
}

// Round 13
// 113.376 us; speedup vs baseline: 1.3829x; 1.3829x over previous
//
#include <hip/hip_runtime.h>

#define SQRT2f 1.41421356237309515f
#define SQRT3f 1.73205080756887729f

__device__ __forceinline__ float2 cmul(float2 a, float2 b) {
  return make_float2(a.x*b.x - a.y*b.y, a.x*b.y + a.y*b.x);
}
__device__ __forceinline__ float2 cadd(float2 a, float2 b) {
  return make_float2(a.x + b.x, a.y + b.y);
}

// ---- BS 9x9 on nine NAMED float2 lvalues q(3*na+nb); rows 0,8 identity ----
#define BS9N(q0,q1,q2,q3,q4,q5,q6,q7,q8, cs) { \
  const float c_ = (cs).x, s_ = (cs).y; \
  const float c2_ = c_*c_ - s_*s_, s2_ = 2.f*c_*s_; \
  const float cc_ = c_*c_, ss_ = s_*s_, rcs_ = SQRT2f*c_*s_; \
  float2 t1=q1, t3=q3, t2=q2, t4=q4, t6=q6, t5=q5, t7=q7; \
  q1 = make_float2(c_*t1.x - s_*t3.x, c_*t1.y - s_*t3.y); \
  q3 = make_float2(s_*t1.x + c_*t3.x, s_*t1.y + c_*t3.y); \
  q2 = make_float2(cc_*t2.x - rcs_*t4.x + ss_*t6.x, cc_*t2.y - rcs_*t4.y + ss_*t6.y); \
  q4 = make_float2(rcs_*t2.x + c2_*t4.x - rcs_*t6.x, rcs_*t2.y + c2_*t4.y - rcs_*t6.y); \
  q6 = make_float2(ss_*t2.x + rcs_*t4.x + cc_*t6.x, ss_*t2.y + rcs_*t4.y + cc_*t6.y); \
  q5 = make_float2(c2_*t5.x - s2_*t7.x, c2_*t5.y - s2_*t7.y); \
  q7 = make_float2(s2_*t5.x + c2_*t7.x, s2_*t5.y + c2_*t7.y); }

// ---- plain BS nonet (81-thread sweeps), in place ----
template<int SP>
__device__ __forceinline__ void bs_nonet(float2* __restrict__ psi, int base,
                                         float2 cs) {
  float2 q1 = psi[base+SP],   q3 = psi[base+3*SP];
  float2 q2 = psi[base+2*SP], q4 = psi[base+4*SP], q6 = psi[base+6*SP];
  float2 q5 = psi[base+5*SP], q7 = psi[base+7*SP];
  float2 q0, q8;  // unused rows
  (void)q0; (void)q8;
  BS9N(q0, q1, q2, q3, q4, q5, q6, q7, q8, cs);
  psi[base+SP]   = q1;  psi[base+3*SP] = q3;
  psi[base+2*SP] = q2;  psi[base+4*SP] = q4;  psi[base+6*SP] = q6;
  psi[base+5*SP] = q5;  psi[base+7*SP] = q7;
}

// ---- fused (SQ_A ⊗ SQ_B) then BS, pair (0,1), scalarized ----
template<int SP>
__device__ __forceinline__ void sqbs_nonet(float2* __restrict__ psi, int base,
                                           const float2* __restrict__ G,
                                           float2 cs) {
  float2 A00=G[0],A02=G[1],A11=G[2],A20=G[3],A22=G[4];
  float2 B00=G[5],B02=G[6],B11=G[7],B20=G[8],B22=G[9];
  float2 v00 = psi[base],        v01 = psi[base+SP],     v02 = psi[base+2*SP];
  float2 v10 = psi[base+3*SP],   v11 = psi[base+4*SP],   v12 = psi[base+5*SP];
  float2 v20 = psi[base+6*SP],   v21 = psi[base+7*SP],   v22 = psi[base+8*SP];
  // B along inner (col), then A along outer (row)
  { float2 u0=v00,u2=v02; v00=cadd(cmul(B00,u0),cmul(B02,u2)); v01=cmul(B11,v01); v02=cadd(cmul(B20,u0),cmul(B22,u2)); }
  { float2 u0=v10,u2=v12; v10=cadd(cmul(B00,u0),cmul(B02,u2)); v11=cmul(B11,v11); v12=cadd(cmul(B20,u0),cmul(B22,u2)); }
  { float2 u0=v20,u2=v22; v20=cadd(cmul(B00,u0),cmul(B02,u2)); v21=cmul(B11,v21); v22=cadd(cmul(B20,u0),cmul(B22,u2)); }
  { float2 u0=v00,u2=v20; v00=cadd(cmul(A00,u0),cmul(A02,u2)); v10=cmul(A11,v10); v20=cadd(cmul(A20,u0),cmul(A22,u2)); }
  { float2 u0=v01,u2=v21; v01=cadd(cmul(A00,u0),cmul(A02,u2)); v11=cmul(A11,v11); v21=cadd(cmul(A20,u0),cmul(A22,u2)); }
  { float2 u0=v02,u2=v22; v02=cadd(cmul(A00,u0),cmul(A02,u2)); v12=cmul(A11,v12); v22=cadd(cmul(A20,u0),cmul(A22,u2)); }
  BS9N(v00,v01,v02,v10,v11,v12,v20,v21,v22, cs);
  psi[base]      = v00; psi[base+SP]   = v01; psi[base+2*SP] = v02;
  psi[base+3*SP] = v10; psi[base+4*SP] = v11; psi[base+5*SP] = v12;
  psi[base+6*SP] = v20; psi[base+7*SP] = v21; psi[base+8*SP] = v22;
}

// ---- fused (DPK_A ⊗ DPK_B dense) then BS, pair (0,1), scalarized ----
template<int SP>
__device__ __forceinline__ void dpbs_nonet(float2* __restrict__ psi, int base,
                                           const float2* __restrict__ G,
                                           float2 cs) {
  float2 v00 = psi[base],        v01 = psi[base+SP],     v02 = psi[base+2*SP];
  float2 v10 = psi[base+3*SP],   v11 = psi[base+4*SP],   v12 = psi[base+5*SP];
  float2 v20 = psi[base+6*SP],   v21 = psi[base+7*SP],   v22 = psi[base+8*SP];
  {
    float2 B0=G[9],B1=G[10],B2=G[11],B3=G[12],B4=G[13],B5=G[14],B6=G[15],B7=G[16],B8=G[17];
    { float2 u0=v00,u1=v01,u2=v02;
      v00=cadd(cadd(cmul(B0,u0),cmul(B1,u1)),cmul(B2,u2));
      v01=cadd(cadd(cmul(B3,u0),cmul(B4,u1)),cmul(B5,u2));
      v02=cadd(cadd(cmul(B6,u0),cmul(B7,u1)),cmul(B8,u2)); }
    { float2 u0=v10,u1=v11,u2=v12;
      v10=cadd(cadd(cmul(B0,u0),cmul(B1,u1)),cmul(B2,u2));
      v11=cadd(cadd(cmul(B3,u0),cmul(B4,u1)),cmul(B5,u2));
      v12=cadd(cadd(cmul(B6,u0),cmul(B7,u1)),cmul(B8,u2)); }
    { float2 u0=v20,u1=v21,u2=v22;
      v20=cadd(cadd(cmul(B0,u0),cmul(B1,u1)),cmul(B2,u2));
      v21=cadd(cadd(cmul(B3,u0),cmul(B4,u1)),cmul(B5,u2));
      v22=cadd(cadd(cmul(B6,u0),cmul(B7,u1)),cmul(B8,u2)); }
  }
  {
    float2 A0=G[0],A1=G[1],A2=G[2],A3=G[3],A4=G[4],A5=G[5],A6=G[6],A7=G[7],A8=G[8];
    { float2 u0=v00,u1=v10,u2=v20;
      v00=cadd(cadd(cmul(A0,u0),cmul(A1,u1)),cmul(A2,u2));
      v10=cadd(cadd(cmul(A3,u0),cmul(A4,u1)),cmul(A5,u2));
      v20=cadd(cadd(cmul(A6,u0),cmul(A7,u1)),cmul(A8,u2)); }
    { float2 u0=v01,u1=v11,u2=v21;
      v01=cadd(cadd(cmul(A0,u0),cmul(A1,u1)),cmul(A2,u2));
      v11=cadd(cadd(cmul(A3,u0),cmul(A4,u1)),cmul(A5,u2));
      v21=cadd(cadd(cmul(A6,u0),cmul(A7,u1)),cmul(A8,u2)); }
    { float2 u0=v02,u1=v12,u2=v22;
      v02=cadd(cadd(cmul(A0,u0),cmul(A1,u1)),cmul(A2,u2));
      v12=cadd(cadd(cmul(A3,u0),cmul(A4,u1)),cmul(A5,u2));
      v22=cadd(cadd(cmul(A6,u0),cmul(A7,u1)),cmul(A8,u2)); }
  }
  BS9N(v00,v01,v02,v10,v11,v12,v20,v21,v22, cs);
  psi[base]      = v00; psi[base+SP]   = v01; psi[base+2*SP] = v02;
  psi[base+3*SP] = v10; psi[base+4*SP] = v11; psi[base+5*SP] = v12;
  psi[base+6*SP] = v20; psi[base+7*SP] = v21; psi[base+8*SP] = v22;
}

// ---- 81-thread cube sweep, fully scalarized (no arrays -> no scratch).
// Thread (cube, h) holds plane hi=h as v(mid,lo); fold + BS(mid,lo) local;
// rotate-offset shuffles re-partition to plane lo=h; BS(hi,mid); write back.
template<int FOLD, int SH, int SM, int SL>
__device__ __forceinline__ void cube81s(float2* __restrict__ psi, int base,
                                        int h, int lb3,
                                        const float2* __restrict__ G,
                                        float2 csM, float2 csH) {
  const int rb = base + h*SH;
  float2 v00 = psi[rb],          v01 = psi[rb+SL],       v02 = psi[rb+2*SL];
  float2 v10 = psi[rb+SM],       v11 = psi[rb+SM+SL],    v12 = psi[rb+SM+2*SL];
  float2 v20 = psi[rb+2*SM],     v21 = psi[rb+2*SM+SL],  v22 = psi[rb+2*SM+2*SL];
  if (FOLD == 1) {  // sparse SQ: A(5) on mid, B(5) on lo
    float2 A00=G[0],A02=G[1],A11=G[2],A20=G[3],A22=G[4];
    float2 B00=G[5],B02=G[6],B11=G[7],B20=G[8],B22=G[9];
    { float2 u0=v00,u2=v02; v00=cadd(cmul(B00,u0),cmul(B02,u2)); v01=cmul(B11,v01); v02=cadd(cmul(B20,u0),cmul(B22,u2)); }
    { float2 u0=v10,u2=v12; v10=cadd(cmul(B00,u0),cmul(B02,u2)); v11=cmul(B11,v11); v12=cadd(cmul(B20,u0),cmul(B22,u2)); }
    { float2 u0=v20,u2=v22; v20=cadd(cmul(B00,u0),cmul(B02,u2)); v21=cmul(B11,v21); v22=cadd(cmul(B20,u0),cmul(B22,u2)); }
    { float2 u0=v00,u2=v20; v00=cadd(cmul(A00,u0),cmul(A02,u2)); v10=cmul(A11,v10); v20=cadd(cmul(A20,u0),cmul(A22,u2)); }
    { float2 u0=v01,u2=v21; v01=cadd(cmul(A00,u0),cmul(A02,u2)); v11=cmul(A11,v11); v21=cadd(cmul(A20,u0),cmul(A22,u2)); }
    { float2 u0=v02,u2=v22; v02=cadd(cmul(A00,u0),cmul(A02,u2)); v12=cmul(A11,v12); v22=cadd(cmul(A20,u0),cmul(A22,u2)); }
  }
  if (FOLD == 2) {  // dense DPK: A(9) on mid, B(9) on lo
    {
      float2 B0=G[9],B1=G[10],B2=G[11],B3=G[12],B4=G[13],B5=G[14],B6=G[15],B7=G[16],B8=G[17];
      { float2 u0=v00,u1=v01,u2=v02;
        v00=cadd(cadd(cmul(B0,u0),cmul(B1,u1)),cmul(B2,u2));
        v01=cadd(cadd(cmul(B3,u0),cmul(B4,u1)),cmul(B5,u2));
        v02=cadd(cadd(cmul(B6,u0),cmul(B7,u1)),cmul(B8,u2)); }
      { float2 u0=v10,u1=v11,u2=v12;
        v10=cadd(cadd(cmul(B0,u0),cmul(B1,u1)),cmul(B2,u2));
        v11=cadd(cadd(cmul(B3,u0),cmul(B4,u1)),cmul(B5,u2));
        v12=cadd(cadd(cmul(B6,u0),cmul(B7,u1)),cmul(B8,u2)); }
      { float2 u0=v20,u1=v21,u2=v22;
        v20=cadd(cadd(cmul(B0,u0),cmul(B1,u1)),cmul(B2,u2));
        v21=cadd(cadd(cmul(B3,u0),cmul(B4,u1)),cmul(B5,u2));
        v22=cadd(cadd(cmul(B6,u0),cmul(B7,u1)),cmul(B8,u2)); }
    }
    {
      float2 A0=G[0],A1=G[1],A2=G[2],A3=G[3],A4=G[4],A5=G[5],A6=G[6],A7=G[7],A8=G[8];
      { float2 u0=v00,u1=v10,u2=v20;
        v00=cadd(cadd(cmul(A0,u0),cmul(A1,u1)),cmul(A2,u2));
        v10=cadd(cadd(cmul(A3,u0),cmul(A4,u1)),cmul(A5,u2));
        v20=cadd(cadd(cmul(A6,u0),cmul(A7,u1)),cmul(A8,u2)); }
      { float2 u0=v01,u1=v11,u2=v21;
        v01=cadd(cadd(cmul(A0,u0),cmul(A1,u1)),cmul(A2,u2));
        v11=cadd(cadd(cmul(A3,u0),cmul(A4,u1)),cmul(A5,u2));
        v21=cadd(cadd(cmul(A6,u0),cmul(A7,u1)),cmul(A8,u2)); }
      { float2 u0=v02,u1=v12,u2=v22;
        v02=cadd(cadd(cmul(A0,u0),cmul(A1,u1)),cmul(A2,u2));
        v12=cadd(cadd(cmul(A3,u0),cmul(A4,u1)),cmul(A5,u2));
        v22=cadd(cadd(cmul(A6,u0),cmul(A7,u1)),cmul(A8,u2)); }
    }
  }
  BS9N(v00,v01,v02,v10,v11,v12,v20,v21,v22, csM);   // BS(mid,lo)
  // Re-partition (r11-verified rotate-offset): thread h needs amp(hi,m,lo=h).
  const int hp1 = (h==2) ? 0 : h+1;
  const int hp2 = (h==0) ? 2 : h-1;
  const int l1 = lb3 + hp1, l2 = lb3 + hp2;
  float2 own0 = (h==0)?v00:(h==1)?v01:v02;
  float2 e1_0 = (h==0)?v02:(h==1)?v00:v01;
  float2 e2_0 = (h==0)?v01:(h==1)?v02:v00;
  float2 own1 = (h==0)?v10:(h==1)?v11:v12;
  float2 e1_1 = (h==0)?v12:(h==1)?v10:v11;
  float2 e2_1 = (h==0)?v11:(h==1)?v12:v10;
  float2 own2 = (h==0)?v20:(h==1)?v21:v22;
  float2 e1_2 = (h==0)?v22:(h==1)?v20:v21;
  float2 e2_2 = (h==0)?v21:(h==1)?v22:v20;
  float2 r1_0, r2_0, r1_1, r2_1, r1_2, r2_2;
  r1_0.x = __shfl(e1_0.x, l1, 64); r1_0.y = __shfl(e1_0.y, l1, 64);
  r2_0.x = __shfl(e2_0.x, l2, 64); r2_0.y = __shfl(e2_0.y, l2, 64);
  r1_1.x = __shfl(e1_1.x, l1, 64); r1_1.y = __shfl(e1_1.y, l1, 64);
  r2_1.x = __shfl(e2_1.x, l2, 64); r2_1.y = __shfl(e2_1.y, l2, 64);
  r1_2.x = __shfl(e1_2.x, l1, 64); r1_2.y = __shfl(e1_2.y, l1, 64);
  r2_2.x = __shfl(e2_2.x, l2, 64); r2_2.y = __shfl(e2_2.y, l2, 64);
  // a(hi,m): hi==h -> own_m; hi==(h+1)%3 -> r1_m; hi==(h+2)%3 -> r2_m
  float2 a00 = (h==0)?own0:(h==2)?r1_0:r2_0;
  float2 a01 = (h==0)?own1:(h==2)?r1_1:r2_1;
  float2 a02 = (h==0)?own2:(h==2)?r1_2:r2_2;
  float2 a10 = (h==1)?own0:(h==0)?r1_0:r2_0;
  float2 a11 = (h==1)?own1:(h==0)?r1_1:r2_1;
  float2 a12 = (h==1)?own2:(h==0)?r1_2:r2_2;
  float2 a20 = (h==2)?own0:(h==1)?r1_0:r2_0;
  float2 a21 = (h==2)?own1:(h==1)?r1_1:r2_1;
  float2 a22 = (h==2)?own2:(h==1)?r1_2:r2_2;
  BS9N(a00,a01,a02,a10,a11,a12,a20,a21,a22, csH);   // BS(hi,mid)
  const int wb = base + h*SL;
  psi[wb]           = a00; psi[wb+SM]      = a01; psi[wb+2*SM]      = a02;
  psi[wb+SH]        = a10; psi[wb+SH+SM]   = a11; psi[wb+SH+2*SM]   = a12;
  psi[wb+2*SH]      = a20; psi[wb+2*SH+SM] = a21; psi[wb+2*SH+2*SM] = a22;
}

#define BASE4(g, s0,s1,s2,s3) ({ int _d=(g); int _b=(_d%3)*(s0); _d/=3; \
  _b += (_d%3)*(s1); _d/=3; _b += (_d%3)*(s2); _d/=3; _b += (_d%3)*(s3); _b; })
#define BASE5(g, s0,s1,s2,s3,s4) ({ int _d=(g); int _b=(_d%3)*(s0); _d/=3; \
  _b += (_d%3)*(s1); _d/=3; _b += (_d%3)*(s2); _d/=3; _b += (_d%3)*(s3); _d/=3; \
  _b += (_d%3)*(s4); _b; })

// DPK(L,mode)[i][j] = Kerr_i * U_disp[i][j] * phase^j (th2-layer phases)
__device__ __forceinline__ float2 dpk_entry(const float* __restrict__ dr,
                                            const float* __restrict__ th2,
                                            const float* __restrict__ kp,
                                            int L, int mode, int i, int j) {
  float sn, cn; sincosf(SQRT3f*dr[L*6+mode], &sn, &cn);
  float sw = sn*(1.f/SQRT3f), cw = (1.f-cn)*(1.f/3.f);
  float U;
  if      (i==0) U = (j==0) ? (1.f-cw)     : (j==1) ? (-sw)         : (SQRT2f*cw);
  else if (i==1) U = (j==0) ? (sw)         : (j==1) ? (1.f-3.f*cw)  : (-SQRT2f*sw);
  else           U = (j==0) ? (SQRT2f*cw)  : (j==1) ? (SQRT2f*sw)   : (1.f-2.f*cw);
  float2 ph = make_float2(1.f, 0.f);
  if (mode < 5) { float ps, pc; sincosf(th2[L*35+29+mode], &ps, &pc);
                  ph = make_float2(pc, ps); }
  float2 phj = (j==0) ? make_float2(1.f,0.f) : (j==1) ? ph : cmul(ph, ph);
  float ks, kc; sincosf(0.001f*kp[L*6+mode], &ks, &kc);
  float2 k1 = make_float2(kc, ks);
  float2 ki = (i==0) ? make_float2(1.f,0.f)
            : (i==1) ? k1 : cmul(cmul(k1,k1), cmul(k1,k1));
  float2 t = cmul(phj, ki);
  return make_float2(U*t.x, U*t.y);
}

// gtab (float2):
// [0,180)   BS (c,s): idx = (L*2+pass)*15 + pos (application order)
// [180,360) SQG: 180 + L*30 + c*10 : A(5) mode 2c, B(5) mode 2c+1 (th1 phases)
// [360,630) DPG: 360 + Ls*54 + c*18 : A(9) mode 2c, B(9) mode 2c+1 (layers 0..4)
// [630,684) Meas M_m = DPK(5,m)† X3 DPK(5,m): 630 + m*9 + i*3+j
// [684,690) init disp (sw,cw) per mode
__global__ __launch_bounds__(128)
void cvnn_kernel(const float* __restrict__ x,
                 const float* __restrict__ th1,
                 const float* __restrict__ th2,
                 const float* __restrict__ sr,
                 const float* __restrict__ dr,
                 const float* __restrict__ kp,
                 float* __restrict__ out) {
  __shared__ float2 psi[729];
  __shared__ float2 gtab[690];
  __shared__ float red[12];

  const int tid = threadIdx.x;
  const int bidx = blockIdx.x;

  // ---- build gate table ----
  for (int f = tid; f < 690; f += 128) {
    float sn, cn; float2 v;
    if (f < 180) {
      int Lp = f/15, pos = f%15;
      int L = Lp/2, pass = Lp%2;
      float th = (pass ? th2 : th1)[L*35 + pos];
      sincosf(th, &sn, &cn); v = make_float2(cn, sn);
    } else if (f < 360) {
      int i = f - 180; int Lc = i/10, e = i%10;
      int L = Lc/3, c3 = Lc%3;
      int mode = 2*c3 + (e >= 5); int ee = e%5;
      float Sq, Cq; sincosf(0.25f*SQRT2f*sr[L*6+mode], &Sq, &Cq);
      float2 ph = make_float2(1.f, 0.f);
      if (mode < 5) { float ps, pc; sincosf(th1[L*35+29+mode], &ps, &pc);
                      ph = make_float2(pc, ps); }
      float2 ph2 = cmul(ph, ph);
      if      (ee == 0) v = make_float2(Cq, 0.f);
      else if (ee == 1) v = make_float2(Sq*ph2.x, Sq*ph2.y);
      else if (ee == 2) v = ph;
      else if (ee == 3) v = make_float2(-Sq, 0.f);
      else              v = make_float2(Cq*ph2.x, Cq*ph2.y);
    } else if (f < 630) {
      int i = f - 360; int Ld = i/18, e = i%18;
      int Ls = Ld/3, c3 = Ld%3;
      int mode = 2*c3 + (e >= 9); int ee = e%9;
      v = dpk_entry(dr, th2, kp, Ls, mode, ee/3, ee%3);
    } else if (f < 684) {
      int i = f - 630; int m = i/9, e = i%9;
      int ii = e/3, jj = e%3;
      float2 D0i = dpk_entry(dr, th2, kp, 5, m, 0, ii);
      float2 D1i = dpk_entry(dr, th2, kp, 5, m, 1, ii);
      float2 D2i = dpk_entry(dr, th2, kp, 5, m, 2, ii);
      float2 D0j = dpk_entry(dr, th2, kp, 5, m, 0, jj);
      float2 D1j = dpk_entry(dr, th2, kp, 5, m, 1, jj);
      float2 D2j = dpk_entry(dr, th2, kp, 5, m, 2, jj);
      float2 c0 = make_float2(D0i.x, -D0i.y);
      float2 c1 = make_float2(D1i.x, -D1i.y);
      float2 c2 = make_float2(D2i.x, -D2i.y);
      float2 acc = cmul(c0, D1j);
      float2 tmp = make_float2(D0j.x + SQRT2f*D2j.x, D0j.y + SQRT2f*D2j.y);
      acc = cadd(acc, cmul(c1, tmp));
      acc = cadd(acc, cmul(c2, make_float2(SQRT2f*D1j.x, SQRT2f*D1j.y)));
      v = acc;
    } else {
      int mode = f - 684;
      sincosf(SQRT3f*x[bidx*6 + mode], &sn, &cn);
      v = make_float2(sn*(1.f/SQRT3f), (1.f-cn)*(1.f/3.f));
    }
    gtab[f] = v;
  }
  __syncthreads();

  // ---- init: product state of displaced |0> ----
  for (int idx = tid; idx < 729; idx += 128) {
    float pr = 1.f; int d = idx;
#pragma unroll
    for (int mm = 5; mm >= 0; --mm) {
      int n = d % 3; d /= 3;
      float2 dc = gtab[684 + mm];
      pr *= (n==0) ? (1.f-dc.y) : (n==1) ? dc.x : SQRT2f*dc.y;
    }
    psi[idx] = make_float2(pr, 0.f);
  }

  // ---- per-thread bases ----
  const int g = (tid < 81) ? tid : 0;      // pair(0,1) nonet id (tid<81 active)
  const int b0 = g;                        // SP=81
  // cube threads: triples at consecutive lanes; never straddle a wave
  const int lane = tid & 63, wv = tid >> 6;
  const bool cact = (wv == 0) ? (lane < 63) : (lane < 18);
  const int lc = lane / 3;
  const int cc = (wv == 0) ? lc : (21 + lc);   // cube id 0..26
  const int ch = lane % 3;
  const int lb3 = lc * 3;
  const int q0 = cc/9, q1 = (cc%9)/3, q2 = cc%3;
  const int cbase123 = q0*243 + q1*3 + q2;     // fixed (n0,n4,n5)
  const int cbase345 = q0*243 + q1*81 + q2*27; // fixed (n0,n1,n2)
  __syncthreads();

#define W81_BS(GI)      { if (tid < 81) bs_nonet<81>(psi, b0, gtab[GI]); \
    __syncthreads(); }
#define W81_SQBS(GS,GI) { if (tid < 81) sqbs_nonet<81>(psi, b0, &gtab[GS], gtab[GI]); \
    __syncthreads(); }
#define W81_DPBS(GD,GI) { if (tid < 81) dpbs_nonet<81>(psi, b0, &gtab[GD], gtab[GI]); \
    __syncthreads(); }
#define C123(F,GP,GIM,GIH) { if (cact) \
    cube81s<F,81,27,9>(psi, cbase123, ch, lb3, GP, gtab[GIM], gtab[GIH]); \
    __syncthreads(); }
#define C345(F,GP,GIM,GIH) { if (cact) \
    cube81s<F,9,3,1>(psi, cbase345, ch, lb3, GP, gtab[GIM], gtab[GIH]); \
    __syncthreads(); }

#pragma unroll
  for (int L = 0; L < 6; ++L) {
    {  // th1 pass: folds previous layer's DPK (L>=1)
      const int PB = (L*2)*15;
      if (L == 0) {
        W81_BS(PB+0);
        C123(0, (const float2*)nullptr, PB+1, PB+3);
        C345(0, (const float2*)nullptr, PB+2, PB+4);
      } else {
        const int gd = 360 + (L-1)*54;
        W81_DPBS(gd+0, PB+0);
        C123(2, &gtab[gd+18], PB+1, PB+3);
        C345(2, &gtab[gd+36], PB+2, PB+4);
      }
      W81_BS(PB+5);
      C123(0, (const float2*)nullptr, PB+6, PB+8);
      C345(0, (const float2*)nullptr, PB+7, PB+9);
      W81_BS(PB+10);
      C123(0, (const float2*)nullptr, PB+11, PB+13);
      C345(0, (const float2*)nullptr, PB+12, PB+14);
    }
    {  // th2 pass: folds this layer's SQ (+th1 phases)
      const int PB = (L*2+1)*15, gs = 180 + L*30;
      W81_SQBS(gs+0, PB+0);
      C123(1, &gtab[gs+10], PB+1, PB+3);
      C345(1, &gtab[gs+20], PB+2, PB+4);
      W81_BS(PB+5);
      C123(0, (const float2*)nullptr, PB+6, PB+8);
      C345(0, (const float2*)nullptr, PB+7, PB+9);
      W81_BS(PB+10);
      C123(0, (const float2*)nullptr, PB+11, PB+13);
      C345(0, (const float2*)nullptr, PB+12, PB+14);
    }
  }

  // ---- <X_m> via folded Hermitian M_m = DPK(5,m)† X DPK(5,m) ----
  float xs[6] = {0.f,0.f,0.f,0.f,0.f,0.f};
  for (int it = 0; it < 2; ++it) {
    int t = tid + (it << 7);
    if (t < 243) {
#define XACC(m, SS, BB) { int b_ = (BB); \
      const float2* M_ = &gtab[630 + (m)*9]; \
      float d0 = M_[0].x, d1 = M_[4].x, d2 = M_[8].x; \
      float2 M01 = M_[1], M02 = M_[2], M12 = M_[5]; \
      float2 a_ = psi[b_]; float2 e_ = psi[b_+(SS)]; float2 f_ = psi[b_+2*(SS)]; \
      xs[m] += d0*(a_.x*a_.x + a_.y*a_.y) + d1*(e_.x*e_.x + e_.y*e_.y) \
             + d2*(f_.x*f_.x + f_.y*f_.y) \
        + 2.f*(M01.x*(a_.x*e_.x + a_.y*e_.y) - M01.y*(a_.x*e_.y - a_.y*e_.x)) \
        + 2.f*(M02.x*(a_.x*f_.x + a_.y*f_.y) - M02.y*(a_.x*f_.y - a_.y*f_.x)) \
        + 2.f*(M12.x*(e_.x*f_.x + e_.y*f_.y) - M12.y*(e_.x*f_.y - e_.y*f_.x)); }
      XACC(0, 243, BASE5(t, 1, 3, 9, 27, 81));
      XACC(1, 81,  BASE5(t, 1, 3, 9, 27, 243));
      XACC(2, 27,  BASE5(t, 1, 3, 9, 81, 243));
      XACC(3, 9,   BASE5(t, 1, 3, 27, 81, 243));
      XACC(4, 3,   BASE5(t, 1, 9, 27, 81, 243));
      XACC(5, 1,   BASE5(t, 3, 9, 27, 81, 243));
    }
  }
  const int wid = tid >> 6;
#pragma unroll
  for (int m = 0; m < 6; ++m) {
    float v = xs[m];
    for (int off = 32; off > 0; off >>= 1) v += __shfl_down(v, off);
    if ((tid & 63) == 0) red[wid*6 + m] = v;
  }
  __syncthreads();
  if (tid < 6) out[bidx*6 + tid] = red[tid] + red[6 + tid];
}

extern "C" void kernel_launch(void* const* d_in, const int* in_sizes, int n_in,
                              void* d_out, int out_size, void* d_ws, size_t ws_size,
                              hipStream_t stream) {
  const float* x  = (const float*)d_in[0];
  const float* t1 = (const float*)d_in[1];
  const float* t2 = (const float*)d_in[2];
  const float* sr = (const float*)d_in[3];
  const float* dr = (const float*)d_in[4];
  const float* kp = (const float*)d_in[5];
  const int B = in_sizes[0] / 6;
  cvnn_kernel<<<B, 128, 0, stream>>>(x, t1, t2, sr, dr, kp, (float*)d_out);
}

// Round 14
// 94.725 us; speedup vs baseline: 1.6551x; 1.1969x over previous
//
#include <hip/hip_runtime.h>

#define SQRT2f 1.41421356237309515f
#define SQRT3f 1.73205080756887729f

__device__ __forceinline__ float2 cmul(float2 a, float2 b) {
  return make_float2(a.x*b.x - a.y*b.y, a.x*b.y + a.y*b.x);
}
__device__ __forceinline__ float2 cadd(float2 a, float2 b) {
  return make_float2(a.x + b.x, a.y + b.y);
}

// ---- BS 9x9 on nine NAMED float2 lvalues q(3*na+nb); rows 0,8 identity ----
#define BS9N(q0,q1,q2,q3,q4,q5,q6,q7,q8, cs) { \
  const float c_ = (cs).x, s_ = (cs).y; \
  const float c2_ = c_*c_ - s_*s_, s2_ = 2.f*c_*s_; \
  const float cc_ = c_*c_, ss_ = s_*s_, rcs_ = SQRT2f*c_*s_; \
  float2 t1=q1, t3=q3, t2=q2, t4=q4, t6=q6, t5=q5, t7=q7; \
  q1 = make_float2(c_*t1.x - s_*t3.x, c_*t1.y - s_*t3.y); \
  q3 = make_float2(s_*t1.x + c_*t3.x, s_*t1.y + c_*t3.y); \
  q2 = make_float2(cc_*t2.x - rcs_*t4.x + ss_*t6.x, cc_*t2.y - rcs_*t4.y + ss_*t6.y); \
  q4 = make_float2(rcs_*t2.x + c2_*t4.x - rcs_*t6.x, rcs_*t2.y + c2_*t4.y - rcs_*t6.y); \
  q6 = make_float2(ss_*t2.x + rcs_*t4.x + cc_*t6.x, ss_*t2.y + rcs_*t4.y + cc_*t6.y); \
  q5 = make_float2(c2_*t5.x - s2_*t7.x, c2_*t5.y - s2_*t7.y); \
  q7 = make_float2(s2_*t5.x + c2_*t7.x, s2_*t5.y + c2_*t7.y); }

// ---- plain BS nonet (81-thread sweeps), in place ----
template<int SP>
__device__ __forceinline__ void bs_nonet(float2* __restrict__ psi, int base,
                                         float2 cs) {
  float2 q1 = psi[base+SP],   q3 = psi[base+3*SP];
  float2 q2 = psi[base+2*SP], q4 = psi[base+4*SP], q6 = psi[base+6*SP];
  float2 q5 = psi[base+5*SP], q7 = psi[base+7*SP];
  float2 q0, q8;  // unused rows
  (void)q0; (void)q8;
  BS9N(q0, q1, q2, q3, q4, q5, q6, q7, q8, cs);
  psi[base+SP]   = q1;  psi[base+3*SP] = q3;
  psi[base+2*SP] = q2;  psi[base+4*SP] = q4;  psi[base+6*SP] = q6;
  psi[base+5*SP] = q5;  psi[base+7*SP] = q7;
}

// ---- fused (SQ_A ⊗ SQ_B) then BS, pair (0,1), scalarized ----
template<int SP>
__device__ __forceinline__ void sqbs_nonet(float2* __restrict__ psi, int base,
                                           const float2* __restrict__ G,
                                           float2 cs) {
  float2 A00=G[0],A02=G[1],A11=G[2],A20=G[3],A22=G[4];
  float2 B00=G[5],B02=G[6],B11=G[7],B20=G[8],B22=G[9];
  float2 v00 = psi[base],        v01 = psi[base+SP],     v02 = psi[base+2*SP];
  float2 v10 = psi[base+3*SP],   v11 = psi[base+4*SP],   v12 = psi[base+5*SP];
  float2 v20 = psi[base+6*SP],   v21 = psi[base+7*SP],   v22 = psi[base+8*SP];
  { float2 u0=v00,u2=v02; v00=cadd(cmul(B00,u0),cmul(B02,u2)); v01=cmul(B11,v01); v02=cadd(cmul(B20,u0),cmul(B22,u2)); }
  { float2 u0=v10,u2=v12; v10=cadd(cmul(B00,u0),cmul(B02,u2)); v11=cmul(B11,v11); v12=cadd(cmul(B20,u0),cmul(B22,u2)); }
  { float2 u0=v20,u2=v22; v20=cadd(cmul(B00,u0),cmul(B02,u2)); v21=cmul(B11,v21); v22=cadd(cmul(B20,u0),cmul(B22,u2)); }
  { float2 u0=v00,u2=v20; v00=cadd(cmul(A00,u0),cmul(A02,u2)); v10=cmul(A11,v10); v20=cadd(cmul(A20,u0),cmul(A22,u2)); }
  { float2 u0=v01,u2=v21; v01=cadd(cmul(A00,u0),cmul(A02,u2)); v11=cmul(A11,v11); v21=cadd(cmul(A20,u0),cmul(A22,u2)); }
  { float2 u0=v02,u2=v22; v02=cadd(cmul(A00,u0),cmul(A02,u2)); v12=cmul(A11,v12); v22=cadd(cmul(A20,u0),cmul(A22,u2)); }
  BS9N(v00,v01,v02,v10,v11,v12,v20,v21,v22, cs);
  psi[base]      = v00; psi[base+SP]   = v01; psi[base+2*SP] = v02;
  psi[base+3*SP] = v10; psi[base+4*SP] = v11; psi[base+5*SP] = v12;
  psi[base+6*SP] = v20; psi[base+7*SP] = v21; psi[base+8*SP] = v22;
}

// ---- fused (DPK_A ⊗ DPK_B dense) then BS, pair (0,1), scalarized ----
template<int SP>
__device__ __forceinline__ void dpbs_nonet(float2* __restrict__ psi, int base,
                                           const float2* __restrict__ G,
                                           float2 cs) {
  float2 v00 = psi[base],        v01 = psi[base+SP],     v02 = psi[base+2*SP];
  float2 v10 = psi[base+3*SP],   v11 = psi[base+4*SP],   v12 = psi[base+5*SP];
  float2 v20 = psi[base+6*SP],   v21 = psi[base+7*SP],   v22 = psi[base+8*SP];
  {
    float2 B0=G[9],B1=G[10],B2=G[11],B3=G[12],B4=G[13],B5=G[14],B6=G[15],B7=G[16],B8=G[17];
    { float2 u0=v00,u1=v01,u2=v02;
      v00=cadd(cadd(cmul(B0,u0),cmul(B1,u1)),cmul(B2,u2));
      v01=cadd(cadd(cmul(B3,u0),cmul(B4,u1)),cmul(B5,u2));
      v02=cadd(cadd(cmul(B6,u0),cmul(B7,u1)),cmul(B8,u2)); }
    { float2 u0=v10,u1=v11,u2=v12;
      v10=cadd(cadd(cmul(B0,u0),cmul(B1,u1)),cmul(B2,u2));
      v11=cadd(cadd(cmul(B3,u0),cmul(B4,u1)),cmul(B5,u2));
      v12=cadd(cadd(cmul(B6,u0),cmul(B7,u1)),cmul(B8,u2)); }
    { float2 u0=v20,u1=v21,u2=v22;
      v20=cadd(cadd(cmul(B0,u0),cmul(B1,u1)),cmul(B2,u2));
      v21=cadd(cadd(cmul(B3,u0),cmul(B4,u1)),cmul(B5,u2));
      v22=cadd(cadd(cmul(B6,u0),cmul(B7,u1)),cmul(B8,u2)); }
  }
  {
    float2 A0=G[0],A1=G[1],A2=G[2],A3=G[3],A4=G[4],A5=G[5],A6=G[6],A7=G[7],A8=G[8];
    { float2 u0=v00,u1=v10,u2=v20;
      v00=cadd(cadd(cmul(A0,u0),cmul(A1,u1)),cmul(A2,u2));
      v10=cadd(cadd(cmul(A3,u0),cmul(A4,u1)),cmul(A5,u2));
      v20=cadd(cadd(cmul(A6,u0),cmul(A7,u1)),cmul(A8,u2)); }
    { float2 u0=v01,u1=v11,u2=v21;
      v01=cadd(cadd(cmul(A0,u0),cmul(A1,u1)),cmul(A2,u2));
      v11=cadd(cadd(cmul(A3,u0),cmul(A4,u1)),cmul(A5,u2));
      v21=cadd(cadd(cmul(A6,u0),cmul(A7,u1)),cmul(A8,u2)); }
    { float2 u0=v02,u1=v12,u2=v22;
      v02=cadd(cadd(cmul(A0,u0),cmul(A1,u1)),cmul(A2,u2));
      v12=cadd(cadd(cmul(A3,u0),cmul(A4,u1)),cmul(A5,u2));
      v22=cadd(cadd(cmul(A6,u0),cmul(A7,u1)),cmul(A8,u2)); }
  }
  BS9N(v00,v01,v02,v10,v11,v12,v20,v21,v22, cs);
  psi[base]      = v00; psi[base+SP]   = v01; psi[base+2*SP] = v02;
  psi[base+3*SP] = v10; psi[base+4*SP] = v11; psi[base+5*SP] = v12;
  psi[base+6*SP] = v20; psi[base+7*SP] = v21; psi[base+8*SP] = v22;
}

// ---- 81-thread cube sweep, LDS-mediated (no shuffles/selects, no mid-barrier).
// Stage 1: thread h computes fold + BS(mid,lo) on plane hi=h (read base rb),
// writes back. s_waitcnt lgkmcnt(0): triple partners are in the SAME wave, so
// their writes are retired (per-wave counter). Stage 2: read plane lo=h
// (write base wb; read/write sets disjoint per thread), BS(hi,mid), write.
template<int FOLD, int SH, int SM, int SL>
__device__ __forceinline__ void cube81L(float2* __restrict__ psi, int rb, int wb,
                                        const float2* __restrict__ G,
                                        float2 csM, float2 csH) {
  float2 v00 = psi[rb],          v01 = psi[rb+SL],       v02 = psi[rb+2*SL];
  float2 v10 = psi[rb+SM],       v11 = psi[rb+SM+SL],    v12 = psi[rb+SM+2*SL];
  float2 v20 = psi[rb+2*SM],     v21 = psi[rb+2*SM+SL],  v22 = psi[rb+2*SM+2*SL];
  if (FOLD == 1) {  // sparse SQ: A(5) on mid, B(5) on lo
    float2 A00=G[0],A02=G[1],A11=G[2],A20=G[3],A22=G[4];
    float2 B00=G[5],B02=G[6],B11=G[7],B20=G[8],B22=G[9];
    { float2 u0=v00,u2=v02; v00=cadd(cmul(B00,u0),cmul(B02,u2)); v01=cmul(B11,v01); v02=cadd(cmul(B20,u0),cmul(B22,u2)); }
    { float2 u0=v10,u2=v12; v10=cadd(cmul(B00,u0),cmul(B02,u2)); v11=cmul(B11,v11); v12=cadd(cmul(B20,u0),cmul(B22,u2)); }
    { float2 u0=v20,u2=v22; v20=cadd(cmul(B00,u0),cmul(B02,u2)); v21=cmul(B11,v21); v22=cadd(cmul(B20,u0),cmul(B22,u2)); }
    { float2 u0=v00,u2=v20; v00=cadd(cmul(A00,u0),cmul(A02,u2)); v10=cmul(A11,v10); v20=cadd(cmul(A20,u0),cmul(A22,u2)); }
    { float2 u0=v01,u2=v21; v01=cadd(cmul(A00,u0),cmul(A02,u2)); v11=cmul(A11,v11); v21=cadd(cmul(A20,u0),cmul(A22,u2)); }
    { float2 u0=v02,u2=v22; v02=cadd(cmul(A00,u0),cmul(A02,u2)); v12=cmul(A11,v12); v22=cadd(cmul(A20,u0),cmul(A22,u2)); }
  }
  if (FOLD == 2) {  // dense DPK: A(9) on mid, B(9) on lo
    {
      float2 B0=G[9],B1=G[10],B2=G[11],B3=G[12],B4=G[13],B5=G[14],B6=G[15],B7=G[16],B8=G[17];
      { float2 u0=v00,u1=v01,u2=v02;
        v00=cadd(cadd(cmul(B0,u0),cmul(B1,u1)),cmul(B2,u2));
        v01=cadd(cadd(cmul(B3,u0),cmul(B4,u1)),cmul(B5,u2));
        v02=cadd(cadd(cmul(B6,u0),cmul(B7,u1)),cmul(B8,u2)); }
      { float2 u0=v10,u1=v11,u2=v12;
        v10=cadd(cadd(cmul(B0,u0),cmul(B1,u1)),cmul(B2,u2));
        v11=cadd(cadd(cmul(B3,u0),cmul(B4,u1)),cmul(B5,u2));
        v12=cadd(cadd(cmul(B6,u0),cmul(B7,u1)),cmul(B8,u2)); }
      { float2 u0=v20,u1=v21,u2=v22;
        v20=cadd(cadd(cmul(B0,u0),cmul(B1,u1)),cmul(B2,u2));
        v21=cadd(cadd(cmul(B3,u0),cmul(B4,u1)),cmul(B5,u2));
        v22=cadd(cadd(cmul(B6,u0),cmul(B7,u1)),cmul(B8,u2)); }
    }
    {
      float2 A0=G[0],A1=G[1],A2=G[2],A3=G[3],A4=G[4],A5=G[5],A6=G[6],A7=G[7],A8=G[8];
      { float2 u0=v00,u1=v10,u2=v20;
        v00=cadd(cadd(cmul(A0,u0),cmul(A1,u1)),cmul(A2,u2));
        v10=cadd(cadd(cmul(A3,u0),cmul(A4,u1)),cmul(A5,u2));
        v20=cadd(cadd(cmul(A6,u0),cmul(A7,u1)),cmul(A8,u2)); }
      { float2 u0=v01,u1=v11,u2=v21;
        v01=cadd(cadd(cmul(A0,u0),cmul(A1,u1)),cmul(A2,u2));
        v11=cadd(cadd(cmul(A3,u0),cmul(A4,u1)),cmul(A5,u2));
        v21=cadd(cadd(cmul(A6,u0),cmul(A7,u1)),cmul(A8,u2)); }
      { float2 u0=v02,u1=v12,u2=v22;
        v02=cadd(cadd(cmul(A0,u0),cmul(A1,u1)),cmul(A2,u2));
        v12=cadd(cadd(cmul(A3,u0),cmul(A4,u1)),cmul(A5,u2));
        v22=cadd(cadd(cmul(A6,u0),cmul(A7,u1)),cmul(A8,u2)); }
    }
  }
  BS9N(v00,v01,v02,v10,v11,v12,v20,v21,v22, csM);   // BS(mid,lo)
  psi[rb]         = v00; psi[rb+SL]      = v01; psi[rb+2*SL]      = v02;
  psi[rb+SM]      = v10; psi[rb+SM+SL]   = v11; psi[rb+SM+2*SL]   = v12;
  psi[rb+2*SM]    = v20; psi[rb+2*SM+SL] = v21; psi[rb+2*SM+2*SL] = v22;
  asm volatile("s_waitcnt lgkmcnt(0)" ::: "memory");
  __builtin_amdgcn_sched_barrier(0);
  // Stage 2: plane lo=h — a(hi,m) at wb + hi*SH + m*SM (self-disjoint sets)
  float2 a00 = psi[wb],          a01 = psi[wb+SM],       a02 = psi[wb+2*SM];
  float2 a10 = psi[wb+SH],       a11 = psi[wb+SH+SM],    a12 = psi[wb+SH+2*SM];
  float2 a20 = psi[wb+2*SH],     a21 = psi[wb+2*SH+SM],  a22 = psi[wb+2*SH+2*SM];
  BS9N(a00,a01,a02,a10,a11,a12,a20,a21,a22, csH);   // BS(hi,mid)
  psi[wb]         = a00; psi[wb+SM]      = a01; psi[wb+2*SM]      = a02;
  psi[wb+SH]      = a10; psi[wb+SH+SM]   = a11; psi[wb+SH+2*SM]   = a12;
  psi[wb+2*SH]    = a20; psi[wb+2*SH+SM] = a21; psi[wb+2*SH+2*SM] = a22;
}

#define BASE5(g, s0,s1,s2,s3,s4) ({ int _d=(g); int _b=(_d%3)*(s0); _d/=3; \
  _b += (_d%3)*(s1); _d/=3; _b += (_d%3)*(s2); _d/=3; _b += (_d%3)*(s3); _d/=3; \
  _b += (_d%3)*(s4); _b; })

// DPK(L,mode)[i][j] = Kerr_i * U_disp[i][j] * phase^j (th2-layer phases)
__device__ __forceinline__ float2 dpk_entry(const float* __restrict__ dr,
                                            const float* __restrict__ th2,
                                            const float* __restrict__ kp,
                                            int L, int mode, int i, int j) {
  float sn, cn; sincosf(SQRT3f*dr[L*6+mode], &sn, &cn);
  float sw = sn*(1.f/SQRT3f), cw = (1.f-cn)*(1.f/3.f);
  float U;
  if      (i==0) U = (j==0) ? (1.f-cw)     : (j==1) ? (-sw)         : (SQRT2f*cw);
  else if (i==1) U = (j==0) ? (sw)         : (j==1) ? (1.f-3.f*cw)  : (-SQRT2f*sw);
  else           U = (j==0) ? (SQRT2f*cw)  : (j==1) ? (SQRT2f*sw)   : (1.f-2.f*cw);
  float2 ph = make_float2(1.f, 0.f);
  if (mode < 5) { float ps, pc; sincosf(th2[L*35+29+mode], &ps, &pc);
                  ph = make_float2(pc, ps); }
  float2 phj = (j==0) ? make_float2(1.f,0.f) : (j==1) ? ph : cmul(ph, ph);
  float ks, kc; sincosf(0.001f*kp[L*6+mode], &ks, &kc);
  float2 k1 = make_float2(kc, ks);
  float2 ki = (i==0) ? make_float2(1.f,0.f)
            : (i==1) ? k1 : cmul(cmul(k1,k1), cmul(k1,k1));
  float2 t = cmul(phj, ki);
  return make_float2(U*t.x, U*t.y);
}

// gtab (float2):
// [0,180)   BS (c,s): idx = (L*2+pass)*15 + pos (application order)
// [180,360) SQG: 180 + L*30 + c*10 : A(5) mode 2c, B(5) mode 2c+1 (th1 phases)
// [360,630) DPG: 360 + Ls*54 + c*18 : A(9) mode 2c, B(9) mode 2c+1 (layers 0..4)
// [630,684) Meas M_m = DPK(5,m)† X3 DPK(5,m): 630 + m*9 + i*3+j
// [684,690) init disp (sw,cw) per mode
__global__ __launch_bounds__(128)
void cvnn_kernel(const float* __restrict__ x,
                 const float* __restrict__ th1,
                 const float* __restrict__ th2,
                 const float* __restrict__ sr,
                 const float* __restrict__ dr,
                 const float* __restrict__ kp,
                 float* __restrict__ out) {
  __shared__ float2 psi[729];
  __shared__ float2 gtab[690];
  __shared__ float red[12];

  const int tid = threadIdx.x;
  const int bidx = blockIdx.x;

  // ---- build gate table ----
  for (int f = tid; f < 690; f += 128) {
    float sn, cn; float2 v;
    if (f < 180) {
      int Lp = f/15, pos = f%15;
      int L = Lp/2, pass = Lp%2;
      float th = (pass ? th2 : th1)[L*35 + pos];
      sincosf(th, &sn, &cn); v = make_float2(cn, sn);
    } else if (f < 360) {
      int i = f - 180; int Lc = i/10, e = i%10;
      int L = Lc/3, c3 = Lc%3;
      int mode = 2*c3 + (e >= 5); int ee = e%5;
      float Sq, Cq; sincosf(0.25f*SQRT2f*sr[L*6+mode], &Sq, &Cq);
      float2 ph = make_float2(1.f, 0.f);
      if (mode < 5) { float ps, pc; sincosf(th1[L*35+29+mode], &ps, &pc);
                      ph = make_float2(pc, ps); }
      float2 ph2 = cmul(ph, ph);
      if      (ee == 0) v = make_float2(Cq, 0.f);
      else if (ee == 1) v = make_float2(Sq*ph2.x, Sq*ph2.y);
      else if (ee == 2) v = ph;
      else if (ee == 3) v = make_float2(-Sq, 0.f);
      else              v = make_float2(Cq*ph2.x, Cq*ph2.y);
    } else if (f < 630) {
      int i = f - 360; int Ld = i/18, e = i%18;
      int Ls = Ld/3, c3 = Ld%3;
      int mode = 2*c3 + (e >= 9); int ee = e%9;
      v = dpk_entry(dr, th2, kp, Ls, mode, ee/3, ee%3);
    } else if (f < 684) {
      int i = f - 630; int m = i/9, e = i%9;
      int ii = e/3, jj = e%3;
      float2 D0i = dpk_entry(dr, th2, kp, 5, m, 0, ii);
      float2 D1i = dpk_entry(dr, th2, kp, 5, m, 1, ii);
      float2 D2i = dpk_entry(dr, th2, kp, 5, m, 2, ii);
      float2 D0j = dpk_entry(dr, th2, kp, 5, m, 0, jj);
      float2 D1j = dpk_entry(dr, th2, kp, 5, m, 1, jj);
      float2 D2j = dpk_entry(dr, th2, kp, 5, m, 2, jj);
      float2 c0 = make_float2(D0i.x, -D0i.y);
      float2 c1 = make_float2(D1i.x, -D1i.y);
      float2 c2 = make_float2(D2i.x, -D2i.y);
      float2 acc = cmul(c0, D1j);
      float2 tmp = make_float2(D0j.x + SQRT2f*D2j.x, D0j.y + SQRT2f*D2j.y);
      acc = cadd(acc, cmul(c1, tmp));
      acc = cadd(acc, cmul(c2, make_float2(SQRT2f*D1j.x, SQRT2f*D1j.y)));
      v = acc;
    } else {
      int mode = f - 684;
      sincosf(SQRT3f*x[bidx*6 + mode], &sn, &cn);
      v = make_float2(sn*(1.f/SQRT3f), (1.f-cn)*(1.f/3.f));
    }
    gtab[f] = v;
  }
  __syncthreads();

  // ---- init: product state of displaced |0> ----
  for (int idx = tid; idx < 729; idx += 128) {
    float pr = 1.f; int d = idx;
#pragma unroll
    for (int mm = 5; mm >= 0; --mm) {
      int n = d % 3; d /= 3;
      float2 dc = gtab[684 + mm];
      pr *= (n==0) ? (1.f-dc.y) : (n==1) ? dc.x : SQRT2f*dc.y;
    }
    psi[idx] = make_float2(pr, 0.f);
  }

  // ---- per-thread bases ----
  const int g = (tid < 81) ? tid : 0;      // pair(0,1) nonet id (tid<81 active)
  const int b0 = g;                        // SP=81
  // cube threads: triples at consecutive lanes; never straddle a wave
  const int lane = tid & 63, wv = tid >> 6;
  const bool cact = (wv == 0) ? (lane < 63) : (lane < 18);
  const int lc = lane / 3;
  const int cc = (wv == 0) ? lc : (21 + lc);   // cube id 0..26
  const int ch = lane % 3;
  const int q0 = cc/9, q1 = (cc%9)/3, q2 = cc%3;
  const int cbase123 = q0*243 + q1*3 + q2;     // fixed (n0,n4,n5)
  const int cbase345 = q0*243 + q1*81 + q2*27; // fixed (n0,n1,n2)
  // loop-invariant read/write bases (rb = plane hi=h; wb = plane lo=h)
  const int rb123 = cbase123 + ch*81, wb123 = cbase123 + ch*9;
  const int rb345 = cbase345 + ch*9,  wb345 = cbase345 + ch;
  __syncthreads();

#define W81_BS(GI)      { if (tid < 81) bs_nonet<81>(psi, b0, gtab[GI]); \
    __syncthreads(); }
#define W81_SQBS(GS,GI) { if (tid < 81) sqbs_nonet<81>(psi, b0, &gtab[GS], gtab[GI]); \
    __syncthreads(); }
#define W81_DPBS(GD,GI) { if (tid < 81) dpbs_nonet<81>(psi, b0, &gtab[GD], gtab[GI]); \
    __syncthreads(); }
#define C123(F,GP,GIM,GIH) { if (cact) \
    cube81L<F,81,27,9>(psi, rb123, wb123, GP, gtab[GIM], gtab[GIH]); \
    __syncthreads(); }
#define C345(F,GP,GIM,GIH) { if (cact) \
    cube81L<F,9,3,1>(psi, rb345, wb345, GP, gtab[GIM], gtab[GIH]); \
    __syncthreads(); }

#pragma unroll
  for (int L = 0; L < 6; ++L) {
    {  // th1 pass: folds previous layer's DPK (L>=1)
      const int PB = (L*2)*15;
      if (L == 0) {
        W81_BS(PB+0);
        C123(0, (const float2*)nullptr, PB+1, PB+3);
        C345(0, (const float2*)nullptr, PB+2, PB+4);
      } else {
        const int gd = 360 + (L-1)*54;
        W81_DPBS(gd+0, PB+0);
        C123(2, &gtab[gd+18], PB+1, PB+3);
        C345(2, &gtab[gd+36], PB+2, PB+4);
      }
      W81_BS(PB+5);
      C123(0, (const float2*)nullptr, PB+6, PB+8);
      C345(0, (const float2*)nullptr, PB+7, PB+9);
      W81_BS(PB+10);
      C123(0, (const float2*)nullptr, PB+11, PB+13);
      C345(0, (const float2*)nullptr, PB+12, PB+14);
    }
    {  // th2 pass: folds this layer's SQ (+th1 phases)
      const int PB = (L*2+1)*15, gs = 180 + L*30;
      W81_SQBS(gs+0, PB+0);
      C123(1, &gtab[gs+10], PB+1, PB+3);
      C345(1, &gtab[gs+20], PB+2, PB+4);
      W81_BS(PB+5);
      C123(0, (const float2*)nullptr, PB+6, PB+8);
      C345(0, (const float2*)nullptr, PB+7, PB+9);
      W81_BS(PB+10);
      C123(0, (const float2*)nullptr, PB+11, PB+13);
      C345(0, (const float2*)nullptr, PB+12, PB+14);
    }
  }

  // ---- <X_m> via folded Hermitian M_m = DPK(5,m)† X DPK(5,m) ----
  float xs[6] = {0.f,0.f,0.f,0.f,0.f,0.f};
  for (int it = 0; it < 2; ++it) {
    int t = tid + (it << 7);
    if (t < 243) {
#define XACC(m, SS, BB) { int b_ = (BB); \
      const float2* M_ = &gtab[630 + (m)*9]; \
      float d0 = M_[0].x, d1 = M_[4].x, d2 = M_[8].x; \
      float2 M01 = M_[1], M02 = M_[2], M12 = M_[5]; \
      float2 a_ = psi[b_]; float2 e_ = psi[b_+(SS)]; float2 f_ = psi[b_+2*(SS)]; \
      xs[m] += d0*(a_.x*a_.x + a_.y*a_.y) + d1*(e_.x*e_.x + e_.y*e_.y) \
             + d2*(f_.x*f_.x + f_.y*f_.y) \
        + 2.f*(M01.x*(a_.x*e_.x + a_.y*e_.y) - M01.y*(a_.x*e_.y - a_.y*e_.x)) \
        + 2.f*(M02.x*(a_.x*f_.x + a_.y*f_.y) - M02.y*(a_.x*f_.y - a_.y*f_.x)) \
        + 2.f*(M12.x*(e_.x*f_.x + e_.y*f_.y) - M12.y*(e_.x*f_.y - e_.y*f_.x)); }
      XACC(0, 243, BASE5(t, 1, 3, 9, 27, 81));
      XACC(1, 81,  BASE5(t, 1, 3, 9, 27, 243));
      XACC(2, 27,  BASE5(t, 1, 3, 9, 81, 243));
      XACC(3, 9,   BASE5(t, 1, 3, 27, 81, 243));
      XACC(4, 3,   BASE5(t, 1, 9, 27, 81, 243));
      XACC(5, 1,   BASE5(t, 3, 9, 27, 81, 243));
    }
  }
  const int wid = tid >> 6;
#pragma unroll
  for (int m = 0; m < 6; ++m) {
    float v = xs[m];
    for (int off = 32; off > 0; off >>= 1) v += __shfl_down(v, off);
    if ((tid & 63) == 0) red[wid*6 + m] = v;
  }
  __syncthreads();
  if (tid < 6) out[bidx*6 + tid] = red[tid] + red[6 + tid];
}

extern "C" void kernel_launch(void* const* d_in, const int* in_sizes, int n_in,
                              void* d_out, int out_size, void* d_ws, size_t ws_size,
                              hipStream_t stream) {
  const float* x  = (const float*)d_in[0];
  const float* t1 = (const float*)d_in[1];
  const float* t2 = (const float*)d_in[2];
  const float* sr = (const float*)d_in[3];
  const float* dr = (const float*)d_in[4];
  const float* kp = (const float*)d_in[5];
  const int B = in_sizes[0] / 6;
  cvnn_kernel<<<B, 128, 0, stream>>>(x, t1, t2, sr, dr, kp, (float*)d_out);
}